// Round 5
// baseline (488.026 us; speedup 1.0000x reference)
//
#include <hip/hip_runtime.h>
#include <math.h>

#define D_ 768
#define H_ 3072
#define L_ 256
#define NM_ 256
#define EPS_ 1e-5f
#define SCALE_ 0.036084391824351615f  // 1/sqrt(768)

typedef __attribute__((ext_vector_type(8))) short short8v;
typedef __attribute__((ext_vector_type(4))) float f4v;

__device__ __forceinline__ float wave_sum(float v) {
#pragma unroll
  for (int o = 32; o; o >>= 1) v += __shfl_down(v, o);
  return v;
}

__device__ __forceinline__ unsigned short f2bf(float f) {
  unsigned int u = __float_as_uint(f);
  return (unsigned short)((u + 0x7FFFu + ((u >> 16) & 1u)) >> 16);  // RNE
}

// ---------------- cast weights to bf16: wv, w1, w2 ----------------
__global__ __launch_bounds__(256) void k_cast(const float* __restrict__ s0,
                                              const float* __restrict__ s1,
                                              const float* __restrict__ s2,
                                              short* __restrict__ d0,
                                              short* __restrict__ d1,
                                              short* __restrict__ d2) {
  const float* s;
  short* d;
  int sz;
  if (blockIdx.y == 0) { s = s0; d = d0; sz = D_ * D_; }
  else if (blockIdx.y == 1) { s = s1; d = d1; sz = H_ * D_; }
  else { s = s2; d = d2; sz = D_ * H_; }
  int base = blockIdx.x * 1024 + threadIdx.x * 4;
  if (base >= sz) return;
  float4 v = *(const float4*)&s[base];
  short4 r;
  r.x = (short)f2bf(v.x); r.y = (short)f2bf(v.y);
  r.z = (short)f2bf(v.z); r.w = (short)f2bf(v.w);
  *(short4*)&d[base] = r;
}

// ---------------- qk[d] = scale * sum_j q[j]*wk[j,d],  q = probe@wq.T + bq ----------------
// 12 blocks; each block computes full q redundantly, then its 64 cols of qk.
__global__ __launch_bounds__(256) void k_qk(const float* __restrict__ probe,
                                            const float* __restrict__ wq,
                                            const float* __restrict__ bq,
                                            const float* __restrict__ wk,
                                            float* __restrict__ qk) {
  __shared__ float pr[D_];
  __shared__ float qs[D_];
  __shared__ float part[4][64];
  int t = threadIdx.x;
  for (int i = t; i < D_; i += 256) pr[i] = probe[i];
  __syncthreads();
#pragma unroll
  for (int rr = 0; rr < 3; ++rr) {
    int r = t + rr * 256;
    const float4* w4 = (const float4*)(wq + (size_t)r * D_);
    const float4* p4 = (const float4*)pr;
    float acc = 0.f;
    for (int i = 0; i < 192; ++i) {
      float4 a = w4[i], b = p4[i];
      acc += a.x * b.x + a.y * b.y + a.z * b.z + a.w * b.w;
    }
    qs[r] = (acc + bq[r]) * SCALE_;
  }
  __syncthreads();
  int col = blockIdx.x * 64 + (t & 63);
  int wv_ = t >> 6;
  float acc = 0.f;
  for (int j = wv_ * 192; j < wv_ * 192 + 192; ++j) acc += qs[j] * wk[(size_t)j * D_ + col];
  part[wv_][t & 63] = acc;
  __syncthreads();
  if (t < 64) qk[blockIdx.x * 64 + t] = part[0][t] + part[1][t] + part[2][t] + part[3][t];
}

// ---------------- online-softmax attention pooling (L split in 2) ----------------
#define CHUNK_ 16
#define NCH_ 8  // (L/2)/CHUNK
__global__ __launch_bounds__(256) void k_attnpool(const float* __restrict__ x,
                                                  const float* __restrict__ qk,
                                                  float* __restrict__ pooledP,
                                                  float2* __restrict__ mlP) {
  __shared__ float xs[CHUNK_][D_];  // 48 KB
  __shared__ float sc_s[CHUNK_];
  __shared__ float red[4][D_];      // 12 KB
  int t = threadIdx.x, wave = t >> 6, lane = t & 63;
  int nm = blockIdx.x, part = blockIdx.y;
  const float* xb = x + (size_t)nm * L_ * D_ + (size_t)part * (L_ / 2) * D_;
  // qk fragments for the score pass live in registers
  float4 qr[3];
#pragma unroll
  for (int it = 0; it < 3; ++it) qr[it] = *(const float4*)&qk[(it * 64 + lane) * 4];

  float m_run = -1e30f, l_run = 0.f;
  float acc[3][4];
#pragma unroll
  for (int it = 0; it < 3; ++it)
#pragma unroll
    for (int c = 0; c < 4; ++c) acc[it][c] = 0.f;

  // prefetch chunk 0
  float4 pf[12];
  {
    const float4* src = (const float4*)xb;
#pragma unroll
    for (int i = 0; i < 12; ++i) pf[i] = src[t + i * 256];
  }

  for (int ch = 0; ch < NCH_; ++ch) {
    __syncthreads();  // xs readers done
    {
      float4* dstv = (float4*)&xs[0][0];
#pragma unroll
      for (int i = 0; i < 12; ++i) dstv[t + i * 256] = pf[i];
    }
    __syncthreads();  // xs ready
    if (ch + 1 < NCH_) {
      const float4* nsrc = (const float4*)(xb + (size_t)(ch + 1) * CHUNK_ * D_);
#pragma unroll
      for (int i = 0; i < 12; ++i) pf[i] = nsrc[t + i * 256];
    }
    // scores: wave w handles rows 4w..4w+3
#pragma unroll
    for (int qq = 0; qq < 4; ++qq) {
      int rr = 4 * wave + qq;
      const float4* xr = (const float4*)&xs[rr][0];
      float a = 0.f;
#pragma unroll
      for (int it = 0; it < 3; ++it) {
        float4 xv = xr[it * 64 + lane];
        a += xv.x * qr[it].x + xv.y * qr[it].y + xv.z * qr[it].z + xv.w * qr[it].w;
      }
      a = wave_sum(a);
      if (lane == 0) sc_s[rr] = a;
    }
    __syncthreads();
    float mx = m_run;
#pragma unroll
    for (int i = 0; i < CHUNK_; ++i) mx = fmaxf(mx, sc_s[i]);
    float factor = expf(m_run - mx);
    float psum = 0.f;
#pragma unroll
    for (int i = 0; i < CHUNK_; ++i) psum += expf(sc_s[i] - mx);
    l_run = l_run * factor + psum;
    m_run = mx;
#pragma unroll
    for (int it = 0; it < 3; ++it)
#pragma unroll
      for (int c = 0; c < 4; ++c) acc[it][c] *= factor;
#pragma unroll
    for (int qq = 0; qq < 4; ++qq) {
      int rr = 4 * wave + qq;
      float pq = expf(sc_s[rr] - mx);
      const float4* xr = (const float4*)&xs[rr][0];
#pragma unroll
      for (int it = 0; it < 3; ++it) {
        float4 xv = xr[it * 64 + lane];
        acc[it][0] += pq * xv.x;
        acc[it][1] += pq * xv.y;
        acc[it][2] += pq * xv.z;
        acc[it][3] += pq * xv.w;
      }
    }
  }
#pragma unroll
  for (int it = 0; it < 3; ++it)
    *(float4*)&red[wave][it * 256 + 4 * lane] =
        make_float4(acc[it][0], acc[it][1], acc[it][2], acc[it][3]);
  __syncthreads();
#pragma unroll
  for (int it = 0; it < 3; ++it) {
    int dd = t + it * 256;
    pooledP[((size_t)part * NM_ + nm) * D_ + dd] =
        red[0][dd] + red[1][dd] + red[2][dd] + red[3][dd];
  }
  if (t == 0) mlP[part * NM_ + nm] = make_float2(m_run, l_run);
}

// ---------------- merge two softmax parts -> pooled bf16 ----------------
__global__ __launch_bounds__(256) void k_merge(const float* __restrict__ pooledP,
                                               const float2* __restrict__ mlP,
                                               short* __restrict__ pooled_bf) {
  int t = threadIdx.x, nm = blockIdx.x;
  float2 a = mlP[nm], b = mlP[NM_ + nm];
  float M = fmaxf(a.x, b.x);
  float wa = expf(a.x - M), wb = expf(b.x - M);
  float inv = 1.f / (wa * a.y + wb * b.y);
#pragma unroll
  for (int it = 0; it < 3; ++it) {
    int d = t + it * 256;
    float v = (wa * pooledP[(size_t)nm * D_ + d] + wb * pooledP[(size_t)(NM_ + nm) * D_ + d]) * inv;
    pooled_bf[(size_t)nm * D_ + d] = (short)f2bf(v);
  }
}

// ================= bf16 MFMA GEMM core (64x64 tile, 4 waves, K-step 32) =================
// A[256,K] bf16 row-major; W[N,K] bf16 row-major; C = A @ W^T
#define GEMM_PROLOG(Kval)                                                            \
  __shared__ short A_s[64 * 40];                                                     \
  __shared__ short W_s[64 * 40];                                                     \
  int t = threadIdx.x, wave = t >> 6, lane = t & 63;                                 \
  int wr = wave >> 1, wc = wave & 1;                                                 \
  int fr = lane & 15, fh = lane >> 4;                                                \
  int n0 = blockIdx.x * 64, m0 = blockIdx.y * 64;                                    \
  int srow = t >> 2, sseg = t & 3;                                                   \
  f4v accv[2][2];                                                                    \
  accv[0][0] = (f4v){0.f, 0.f, 0.f, 0.f}; accv[0][1] = (f4v){0.f, 0.f, 0.f, 0.f};   \
  accv[1][0] = (f4v){0.f, 0.f, 0.f, 0.f}; accv[1][1] = (f4v){0.f, 0.f, 0.f, 0.f};

#define GEMM_KLOOP(Abf, Wbf, Kval, k0val, NSTEP)                                     \
  for (int ks = 0; ks < (NSTEP); ++ks) {                                             \
    __syncthreads();                                                                 \
    *(float4*)&A_s[srow * 40 + sseg * 8] =                                           \
        *(const float4*)&(Abf)[(size_t)(m0 + srow) * (Kval) + (k0val) + ks * 32 + sseg * 8]; \
    *(float4*)&W_s[srow * 40 + sseg * 8] =                                           \
        *(const float4*)&(Wbf)[(size_t)(n0 + srow) * (Kval) + (k0val) + ks * 32 + sseg * 8]; \
    __syncthreads();                                                                 \
    short8v a0 = *(short8v*)&A_s[(wr * 32 + fr) * 40 + fh * 8];                      \
    short8v a1 = *(short8v*)&A_s[(wr * 32 + 16 + fr) * 40 + fh * 8];                 \
    short8v b0 = *(short8v*)&W_s[(wc * 32 + fr) * 40 + fh * 8];                      \
    short8v b1 = *(short8v*)&W_s[(wc * 32 + 16 + fr) * 40 + fh * 8];                 \
    accv[0][0] = __builtin_amdgcn_mfma_f32_16x16x32_bf16(a0, b0, accv[0][0], 0, 0, 0); \
    accv[0][1] = __builtin_amdgcn_mfma_f32_16x16x32_bf16(a0, b1, accv[0][1], 0, 0, 0); \
    accv[1][0] = __builtin_amdgcn_mfma_f32_16x16x32_bf16(a1, b0, accv[1][0], 0, 0, 0); \
    accv[1][1] = __builtin_amdgcn_mfma_f32_16x16x32_bf16(a1, b1, accv[1][1], 0, 0, 0); \
  }

// xo = pooled @ wv^T + bv    grid (12,4)
__global__ __launch_bounds__(256) void k_gemm_xo(const short* __restrict__ Abf,
                                                 const short* __restrict__ Wbf,
                                                 const float* __restrict__ bv,
                                                 float* __restrict__ xo) {
  GEMM_PROLOG(D_)
  GEMM_KLOOP(Abf, Wbf, D_, 0, 24)
#pragma unroll
  for (int mi = 0; mi < 2; ++mi)
#pragma unroll
    for (int ni = 0; ni < 2; ++ni)
#pragma unroll
      for (int r = 0; r < 4; ++r) {
        int row = m0 + wr * 32 + mi * 16 + fh * 4 + r;
        int col = n0 + wc * 32 + ni * 16 + fr;
        xo[(size_t)row * D_ + col] = accv[mi][ni][r] + bv[col];
      }
}

// h = gelu(y @ w1^T + b1)   grid (48,4), writes bf16
__global__ __launch_bounds__(256) void k_gemm_gelu(const short* __restrict__ Abf,
                                                   const short* __restrict__ Wbf,
                                                   const float* __restrict__ b1,
                                                   short* __restrict__ h_bf) {
  GEMM_PROLOG(D_)
  GEMM_KLOOP(Abf, Wbf, D_, 0, 24)
#pragma unroll
  for (int mi = 0; mi < 2; ++mi)
#pragma unroll
    for (int ni = 0; ni < 2; ++ni)
#pragma unroll
      for (int r = 0; r < 4; ++r) {
        int row = m0 + wr * 32 + mi * 16 + fh * 4 + r;
        int col = n0 + wc * 32 + ni * 16 + fr;
        float v = accv[mi][ni][r] + b1[col];
        float g = 0.5f * v * (1.f + erff(v * 0.70710678118f));
        h_bf[(size_t)row * H_ + col] = (short)f2bf(g);
      }
}

// op[part] = h @ w2^T (K split 4)   grid (12,4,4)
__global__ __launch_bounds__(256) void k_gemm_o(const short* __restrict__ Abf,
                                                const short* __restrict__ Wbf,
                                                float* __restrict__ op) {
  GEMM_PROLOG(H_)
  int k0 = blockIdx.z * 768;
  GEMM_KLOOP(Abf, Wbf, H_, k0, 24)
  float* dst = op + (size_t)blockIdx.z * NM_ * D_;
#pragma unroll
  for (int mi = 0; mi < 2; ++mi)
#pragma unroll
    for (int ni = 0; ni < 2; ++ni)
#pragma unroll
      for (int r = 0; r < 4; ++r) {
        int row = m0 + wr * 32 + mi * 16 + fh * 4 + r;
        int col = n0 + wc * 32 + ni * 16 + fr;
        dst[(size_t)row * D_ + col] = accv[mi][ni][r];
      }
}

// ---------------- ep1: LN(xo) -> y bf16 ----------------
__global__ __launch_bounds__(256) void k_ep1(const float* __restrict__ xo,
                                             const float* __restrict__ gamma,
                                             const float* __restrict__ beta,
                                             short* __restrict__ y_bf) {
  __shared__ float tmpa[4], tmpb[4];
  int t = threadIdx.x, wave = t >> 6, lane = t & 63;
  int row = blockIdx.x;
  float v[3];
#pragma unroll
  for (int cc = 0; cc < 3; ++cc) v[cc] = xo[(size_t)row * D_ + t + 256 * cc];
  float s = v[0] + v[1] + v[2];
  float ss = v[0] * v[0] + v[1] * v[1] + v[2] * v[2];
#pragma unroll
  for (int o = 32; o; o >>= 1) {
    s += __shfl_down(s, o);
    ss += __shfl_down(ss, o);
  }
  if (lane == 0) { tmpa[wave] = s; tmpb[wave] = ss; }
  __syncthreads();
  float mu = (tmpa[0] + tmpa[1] + tmpa[2] + tmpa[3]) * (1.f / D_);
  float var = (tmpb[0] + tmpb[1] + tmpb[2] + tmpb[3]) * (1.f / D_) - mu * mu;
  float rs = rsqrtf(var + EPS_);
#pragma unroll
  for (int cc = 0; cc < 3; ++cc) {
    int j = t + 256 * cc;
    y_bf[(size_t)row * D_ + j] = (short)f2bf((v[cc] - mu) * rs * gamma[j] + beta[j]);
  }
}

// ---------------- ep3: out = sum_4_parts + b2 + xo ----------------
__global__ __launch_bounds__(256) void k_ep3(const float* __restrict__ op,
                                             const float* __restrict__ b2,
                                             const float* __restrict__ xo,
                                             float* __restrict__ out) {
  int f = (blockIdx.x * 256 + threadIdx.x) * 4;
  int col = f % D_;
  float4 bb = *(const float4*)&b2[col];
  float4 xv = *(const float4*)&xo[f];
  float sx = bb.x + xv.x, sy = bb.y + xv.y, sz = bb.z + xv.z, sw = bb.w + xv.w;
#pragma unroll
  for (int p = 0; p < 4; ++p) {
    float4 pv = *(const float4*)&op[(size_t)p * NM_ * D_ + f];
    sx += pv.x; sy += pv.y; sz += pv.z; sw += pv.w;
  }
  *(float4*)&out[f] = make_float4(sx, sy, sz, sw);
}

extern "C" void kernel_launch(void* const* d_in, const int* in_sizes, int n_in,
                              void* d_out, int out_size, void* d_ws, size_t ws_size,
                              hipStream_t stream) {
  const float* x = (const float*)d_in[0];
  const float* probe = (const float*)d_in[1];
  const float* wq = (const float*)d_in[2];
  const float* bq = (const float*)d_in[3];
  const float* wk = (const float*)d_in[4];
  // d_in[5] = bk: cancels in softmax -> unused
  const float* wv = (const float*)d_in[6];
  const float* bv = (const float*)d_in[7];
  const float* gamma = (const float*)d_in[8];
  const float* beta = (const float*)d_in[9];
  const float* w1 = (const float*)d_in[10];
  const float* b1 = (const float*)d_in[11];
  const float* w2 = (const float*)d_in[12];
  const float* b2 = (const float*)d_in[13];
  float* out = (float*)d_out;

  float* ws = (float*)d_ws;
  float* qk = ws;                                 // 768
  float2* mlP = (float2*)(ws + 768);              // 512 float2 (1024 f)
  float* pooledP = ws + 2048;                     // 2*256*768
  float* xo = ws + 395264;                        // 256*768
  float* op = ws + 591872;                        // 4*256*768
  short* pooled_bf = (short*)(ws + 1378304);      // 256*768 bf16
  short* y_bf = (short*)(ws + 1476608);           // 256*768
  short* h_bf = (short*)(ws + 1574912);           // 256*3072
  short* wv_bf = (short*)(ws + 1968128);          // 768*768
  short* w1_bf = (short*)(ws + 2263040);          // 3072*768
  short* w2_bf = (short*)(ws + 3442688);          // 768*3072

  hipLaunchKernelGGL(k_cast, dim3(2304, 3), dim3(256), 0, stream, wv, w1, w2, wv_bf, w1_bf, w2_bf);
  hipLaunchKernelGGL(k_qk, dim3(12), dim3(256), 0, stream, probe, wq, bq, wk, qk);
  hipLaunchKernelGGL(k_attnpool, dim3(NM_, 2), dim3(256), 0, stream, x, qk, pooledP, mlP);
  hipLaunchKernelGGL(k_merge, dim3(NM_), dim3(256), 0, stream, pooledP, mlP, pooled_bf);
  hipLaunchKernelGGL(k_gemm_xo, dim3(12, 4), dim3(256), 0, stream, pooled_bf, wv_bf, bv, xo);
  hipLaunchKernelGGL(k_ep1, dim3(NM_), dim3(256), 0, stream, xo, gamma, beta, y_bf);
  hipLaunchKernelGGL(k_gemm_gelu, dim3(48, 4), dim3(256), 0, stream, y_bf, w1_bf, b1, h_bf);
  hipLaunchKernelGGL(k_gemm_o, dim3(12, 4, 4), dim3(256), 0, stream, h_bf, w2_bf, op);
  hipLaunchKernelGGL(k_ep3, dim3(192), dim3(256), 0, stream, op, b2, xo, out);
}